// Round 7
// baseline (389.736 us; speedup 1.0000x reference)
//
#include <hip/hip_runtime.h>
#include <hip/hip_bf16.h>

// CfC / liquid-RNN scan on MFMA, R7. fp32 buffers (proven R2).
// R6 post-mortem: SIMD idle ~75% — barrier-lockstep latency-bound; VALU/MFMA
// cuts gave ~nothing. R7 lever: occupancy 16 -> 32 waves/CU (hardware max):
// NPIX=8, 2048 blocks, 8 blocks/CU, launch_bounds(256,8). Per-wave instr
// stream identical to R6; MFMA columns 8..15 carry finite garbage (z/a LDS
// rows 8..15 zero-initialized, never globally stored). Only out-stores
// (ln<8) and x staging (tid<128) are masked.
// Numerics (R6-proven): weights hi+lo split MFMA, activations bf16 hi-only;
// absmax 0.0098 < 0.0199 threshold.

#define CIN      16
#define UNITS    32
#define BACKBONE 64
#define CZ       48
#define TSTEPS   32
#define HW       4096
#define NPIX     8        // real pixels per block (MFMA tile stays 16 wide)
#define LROWS    16       // LDS pixel rows allocated (16-col MFMA tile)
#define NTHREADS 256
#define KPAD     64

typedef __attribute__((ext_vector_type(8))) short  short8;
typedef __attribute__((ext_vector_type(4))) short  short4v;
typedef __attribute__((ext_vector_type(8))) __bf16 bf16x8;
typedef __attribute__((ext_vector_type(4))) float  float4v;

__device__ __forceinline__ unsigned short bf16_rne(float f) {
    unsigned u = __float_as_uint(f);
    return (unsigned short)((u + 0x7FFFu + ((u >> 16) & 1u)) >> 16);
}
__device__ __forceinline__ float bf16_tof(unsigned short h) {
    return __uint_as_float(((unsigned)h) << 16);
}
__device__ __forceinline__ float tanh_fast(float x) {
    float e = __expf(2.0f * x);                 // saturates correctly
    return 1.0f - __fdividef(2.0f, e + 1.0f);
}
__device__ __forceinline__ float sigmoid_fast(float x) {
    return __fdividef(1.0f, 1.0f + __expf(-x));
}
__device__ __forceinline__ float4v mfma16(bf16x8 a, bf16x8 b, float4v c) {
    return __builtin_amdgcn_mfma_f32_16x16x32_bf16(a, b, c, 0, 0, 0);
}
__device__ __forceinline__ void split8(const float* v, bf16x8& hi, bf16x8& lo) {
    short8 sh, sl;
    #pragma unroll
    for (int j = 0; j < 8; ++j) {
        unsigned short h = bf16_rne(v[j]);
        sh[j] = (short)h;
        sl[j] = (short)bf16_rne(v[j] - bf16_tof(h));
    }
    hi = __builtin_bit_cast(bf16x8, sh);
    lo = __builtin_bit_cast(bf16x8, sl);
}
// element (pixel-row p, k) -> ushort offset; 16B chunks xor-swizzled by (p&7)
__device__ __forceinline__ int swoff(int p, int k) {
    return p * KPAD + ((((k >> 3) ^ (p & 7)) << 3) | (k & 7));
}

__global__ __launch_bounds__(NTHREADS, 8)
void cfc_mfma_kernel(const float* __restrict__ x,   const float* __restrict__ Wb,
                     const float* __restrict__ bb,
                     const float* __restrict__ Wff1, const float* __restrict__ bff1,
                     const float* __restrict__ Wff2, const float* __restrict__ bff2,
                     const float* __restrict__ Wta,  const float* __restrict__ bta,
                     const float* __restrict__ Wtb,  const float* __restrict__ btb,
                     float* __restrict__ out)
{
    __shared__ unsigned short zhi[LROWS * KPAD];   // z = [x_t; h], rows 8..15 stay zero
    __shared__ unsigned short ahi[LROWS * KPAD];   // backbone activations

    const int tid  = threadIdx.x;
    const int wave = tid >> 6;
    const int lane = tid & 63;
    const int ln   = lane & 15;     // MFMA m/n
    const int lq   = lane >> 4;     // MFMA quad

    const int gpix = blockIdx.x * NPIX;
    const int b    = gpix >> 12;
    const int pinb = gpix & 4095;

    // ---------------- weights -> VGPR A-fragments (once), hi+lo ----------
    const int mt = wave;                       // backbone m-tile
    bf16x8 Abb_hi[2], Abb_lo[2];
    #pragma unroll
    for (int kt = 0; kt < 2; ++kt) {
        float v[8];
        #pragma unroll
        for (int j = 0; j < 8; ++j) {
            int k  = kt * 32 + lq * 8 + j;
            int ki = (k < CZ) ? k : (CZ - 1);
            float raw = Wb[(mt * 16 + ln) * CZ + ki];
            v[j] = (k < CZ) ? raw : 0.0f;
        }
        split8(v, Abb_hi[kt], Abb_lo[kt]);
    }
    // head weights, row-interleaved: tile row ln -> unit tile*4+(ln>>2), head ln&3
    const int hsel = ln & 3;
    const float* Whp = (hsel == 0) ? Wff1 : (hsel == 1) ? Wff2 : (hsel == 2) ? Wta : Wtb;
    bf16x8 Ah_hi[2][2], Ah_lo[2][2];
    #pragma unroll
    for (int i = 0; i < 2; ++i) {
        const int u = (wave * 2 + i) * 4 + (ln >> 2);
        #pragma unroll
        for (int kt = 0; kt < 2; ++kt) {
            float v[8];
            #pragma unroll
            for (int j = 0; j < 8; ++j) v[j] = Whp[u * BACKBONE + kt * 32 + lq * 8 + j];
            split8(v, Ah_hi[i][kt], Ah_lo[i][kt]);
        }
    }
    // biases in C/D layout
    float bbias[4];
    #pragma unroll
    for (int r = 0; r < 4; ++r) bbias[r] = bb[mt * 16 + lq * 4 + r];
    float hbias[2][4];
    #pragma unroll
    for (int i = 0; i < 2; ++i) {
        const int u2 = (wave * 2 + i) * 4 + lq;
        hbias[i][0] = bff1[u2]; hbias[i][1] = bff2[u2];
        hbias[i][2] = bta[u2];  hbias[i][3] = btb[u2];
    }

    // ---------------- prologue: zero z (h0 + pad rows), stage x_0 --------
    for (int i = tid; i < LROWS * KPAD / 2; i += NTHREADS)
        ((unsigned*)zhi)[i] = 0u;
    __syncthreads();   // zero-fill is cross-wave; must finish before x_0 store

    // x staging: waves 0,1 only (16 channels x 8 pixels = 128 threads)
    const int xc = tid >> 3;           // channel 0..15 (for tid<128)
    const int xp = tid & 7;            // pixel 0..7
    const bool xactive = (tid < 128);  // wave-uniform (waves 0,1)
    const float* xb = x + (size_t)(b * CIN + (xactive ? xc : 0)) * (TSTEPS * HW)
                        + pinb + (xactive ? xp : 0);
    const int xoff = swoff(xp, xc);
    if (xactive) zhi[xoff] = bf16_rne(xb[0]);

    // hoisted per-lane offsets
    const int zrd0 = swoff(ln, lq * 8);            // kt=0 fragment read
    const int zrd1 = swoff(ln, 32 + lq * 8);       // kt=1
    const int awr  = swoff(ln, mt * 16 + lq * 4);  // phase1 act write (4 ushorts)
    const int u0   = (wave * 2 + 0) * 4 + lq;      // phase2 units
    const int u1   = (wave * 2 + 1) * 4 + lq;
    const int ho0  = swoff(ln, CIN + u0);          // h feedback stores
    const int ho1  = swoff(ln, CIN + u1);
    float* po0 = out + (size_t)((b * UNITS + u0) * TSTEPS) * HW + pinb + ln;
    float* po1 = out + (size_t)((b * UNITS + u1) * TSTEPS) * HW + pinb + ln;
    int xoffs = HW;                                // scalar offset of x_{t+1}
    __syncthreads();

    #pragma unroll 1
    for (int t = 0; t < TSTEPS; ++t) {
        // prefetch x_{t+1} (waves 0,1; dummy re-read of x_31 on last iters)
        float xv = 0.0f;
        if (xactive) xv = xb[xoffs];

        // ---- phase 1: backbone 16x16 tile, 4 MFMA, lecun_tanh -> aT ----
        {
            bf16x8 Z0 = __builtin_bit_cast(bf16x8, *(const short8*)&zhi[zrd0]);
            bf16x8 Z1 = __builtin_bit_cast(bf16x8, *(const short8*)&zhi[zrd1]);
            float4v acc = {bbias[0], bbias[1], bbias[2], bbias[3]};
            acc = mfma16(Abb_hi[0], Z0, acc);
            acc = mfma16(Abb_lo[0], Z0, acc);
            acc = mfma16(Abb_hi[1], Z1, acc);
            acc = mfma16(Abb_lo[1], Z1, acc);
            short4v ph;
            #pragma unroll
            for (int r = 0; r < 4; ++r)
                ph[r] = (short)bf16_rne(1.7159f * tanh_fast(0.666f * acc[r]));
            *(short4v*)&ahi[awr] = ph;
        }
        __syncthreads();

        // ---- phase 2: stage x_{t+1}; 4-head interleaved GEMM + gate ----
        {
            bf16x8 A0 = __builtin_bit_cast(bf16x8, *(const short8*)&ahi[zrd0]);
            bf16x8 A1 = __builtin_bit_cast(bf16x8, *(const short8*)&ahi[zrd1]);

            // stage x_{t+1} into z x-rows (no z reader until next barrier)
            if (xactive) zhi[xoff] = bf16_rne(xv);

            {   // tile 0 (units u0)
                float4v acc = {hbias[0][0], hbias[0][1], hbias[0][2], hbias[0][3]};
                acc = mfma16(Ah_hi[0][0], A0, acc);
                acc = mfma16(Ah_lo[0][0], A0, acc);
                acc = mfma16(Ah_hi[0][1], A1, acc);
                acc = mfma16(Ah_lo[0][1], A1, acc);
                float f1 = tanh_fast(acc[0]);
                float f2 = tanh_fast(acc[1]);
                float ti = sigmoid_fast(acc[2] + acc[3]);
                float hn = f1 + ti * (f2 - f1);
                if (ln < NPIX) *po0 = hn;          // pixels 8..15 don't exist
                po0 += HW;
                zhi[ho0] = bf16_rne(hn);           // rows ln<16 exist; finite
            }
            {   // tile 1 (units u1)
                float4v acc = {hbias[1][0], hbias[1][1], hbias[1][2], hbias[1][3]};
                acc = mfma16(Ah_hi[1][0], A0, acc);
                acc = mfma16(Ah_lo[1][0], A0, acc);
                acc = mfma16(Ah_hi[1][1], A1, acc);
                acc = mfma16(Ah_lo[1][1], A1, acc);
                float f1 = tanh_fast(acc[0]);
                float f2 = tanh_fast(acc[1]);
                float ti = sigmoid_fast(acc[2] + acc[3]);
                float hn = f1 + ti * (f2 - f1);
                if (ln < NPIX) *po1 = hn;
                po1 += HW;
                zhi[ho1] = bf16_rne(hn);
            }
        }
        __syncthreads();

        xoffs += (t < TSTEPS - 2) ? HW : 0;   // uniform scalar; clamp at x_31
    }
}

extern "C" void kernel_launch(void* const* d_in, const int* in_sizes, int n_in,
                              void* d_out, int out_size, void* d_ws, size_t ws_size,
                              hipStream_t stream) {
    dim3 grid(4 * HW / NPIX);   // 2048 blocks -> 8 blocks/CU -> 32 waves/CU
    cfc_mfma_kernel<<<grid, NTHREADS, 0, stream>>>(
        (const float*)d_in[0], (const float*)d_in[1], (const float*)d_in[2],
        (const float*)d_in[3], (const float*)d_in[4], (const float*)d_in[5],
        (const float*)d_in[6], (const float*)d_in[7], (const float*)d_in[8],
        (const float*)d_in[9], (const float*)d_in[10],
        (float*)d_out);
}

// Round 8
// 174.299 us; speedup vs baseline: 2.2360x; 2.2360x over previous
//
#include <hip/hip_runtime.h>
#include <hip/hip_bf16.h>

// CfC / liquid-RNN scan, R8: BARRIER-FREE. fp32 buffers (proven R2).
// R7 post-mortem: launch_bounds(256,8) -> VGPR 32 -> weight spill (FETCH
// 34->877 MB), 3.5x regression. Occupancy lever dead (register floor ~80).
// R5-R7 triangulation: the residual cost is 64 block-wide barriers of
// lockstep. R8: ONE WAVE owns a 16-pixel tile end-to-end; the a-transpose
// and h/x feedback go through wave-private LDS ordered by in-wave lgkmcnt —
// zero __syncthreads in the t-loop. 1024 single-wave blocks = 1 wave/SIMD,
// each running unstalled by peers; weights fully resident (~290 VGPRs,
// launch_bounds(64,1) -> no spill).
// Numerics (R6/R7-proven, absmax 0.0098): weights hi+lo bf16 split (2 MFMA
// per k-tile), activations bf16 hi-only. Heads = one 128-row interleaved
// GEMM (row = u*4 + head): lane's 4 acc regs = 4 heads of one unit ->
// in-register gate.

#define CIN      16
#define UNITS    32
#define BACKBONE 64
#define CZ       48
#define TSTEPS   32
#define HW       4096
#define NPIX     16
#define KPAD     64

typedef __attribute__((ext_vector_type(8))) short  short8;
typedef __attribute__((ext_vector_type(4))) short  short4v;
typedef __attribute__((ext_vector_type(8))) __bf16 bf16x8;
typedef __attribute__((ext_vector_type(4))) float  float4v;

__device__ __forceinline__ unsigned short bf16_rne(float f) {
    unsigned u = __float_as_uint(f);
    return (unsigned short)((u + 0x7FFFu + ((u >> 16) & 1u)) >> 16);
}
__device__ __forceinline__ float bf16_tof(unsigned short h) {
    return __uint_as_float(((unsigned)h) << 16);
}
__device__ __forceinline__ float tanh_fast(float x) {
    float e = __expf(2.0f * x);                 // saturates correctly
    return 1.0f - __fdividef(2.0f, e + 1.0f);
}
__device__ __forceinline__ float sigmoid_fast(float x) {
    return __fdividef(1.0f, 1.0f + __expf(-x));
}
__device__ __forceinline__ float4v mfma16(bf16x8 a, bf16x8 b, float4v c) {
    return __builtin_amdgcn_mfma_f32_16x16x32_bf16(a, b, c, 0, 0, 0);
}
__device__ __forceinline__ void split8(const float* v, bf16x8& hi, bf16x8& lo) {
    short8 sh, sl;
    #pragma unroll
    for (int j = 0; j < 8; ++j) {
        unsigned short h = bf16_rne(v[j]);
        sh[j] = (short)h;
        sl[j] = (short)bf16_rne(v[j] - bf16_tof(h));
    }
    hi = __builtin_bit_cast(bf16x8, sh);
    lo = __builtin_bit_cast(bf16x8, sl);
}
// element (pixel-row p, k) -> ushort offset; 16B chunks xor-swizzled by (p&7)
__device__ __forceinline__ int swoff(int p, int k) {
    return p * KPAD + ((((k >> 3) ^ (p & 7)) << 3) | (k & 7));
}

__global__ __launch_bounds__(64, 1)
void cfc_wave_kernel(const float* __restrict__ x,   const float* __restrict__ Wb,
                     const float* __restrict__ bb,
                     const float* __restrict__ Wff1, const float* __restrict__ bff1,
                     const float* __restrict__ Wff2, const float* __restrict__ bff2,
                     const float* __restrict__ Wta,  const float* __restrict__ bta,
                     const float* __restrict__ Wtb,  const float* __restrict__ btb,
                     float* __restrict__ out)
{
    __shared__ unsigned short z[NPIX * KPAD];   // [x_t(k0..15); h(k16..47); 0-pad]
    __shared__ unsigned short a[NPIX * KPAD];   // backbone activations (k0..63)

    const int lane = threadIdx.x;
    const int ln   = lane & 15;     // pixel / MFMA m/n
    const int lq   = lane >> 4;     // MFMA quad

    const int gpix = blockIdx.x * NPIX;
    const int b    = gpix >> 12;
    const int pinb = gpix & 4095;

    // ------------- weights -> VGPR A-fragments (once), hi+lo -------------
    bf16x8 Wbh[4][2], Wbl[4][2];                // backbone: 4 m-tiles
    #pragma unroll
    for (int mt = 0; mt < 4; ++mt)
        #pragma unroll
        for (int kt = 0; kt < 2; ++kt) {
            float v[8];
            #pragma unroll
            for (int j = 0; j < 8; ++j) {
                int k  = kt * 32 + lq * 8 + j;
                int ki = (k < CZ) ? k : (CZ - 1);
                float raw = Wb[(mt * 16 + ln) * CZ + ki];
                v[j] = (k < CZ) ? raw : 0.0f;
            }
            split8(v, Wbh[mt][kt], Wbl[mt][kt]);
        }
    // heads, row-interleaved (row = u*4 + h): tile i row ln -> u=i*4+(ln>>2), head=ln&3
    const int hsel = ln & 3;
    const float* Whp = (hsel == 0) ? Wff1 : (hsel == 1) ? Wff2 : (hsel == 2) ? Wta : Wtb;
    bf16x8 Whh[8][2], Whl[8][2];
    #pragma unroll
    for (int i = 0; i < 8; ++i) {
        const int u = i * 4 + (ln >> 2);
        #pragma unroll
        for (int kt = 0; kt < 2; ++kt) {
            float v[8];
            #pragma unroll
            for (int j = 0; j < 8; ++j) v[j] = Whp[u * BACKBONE + kt * 32 + lq * 8 + j];
            split8(v, Whh[i][kt], Whl[i][kt]);
        }
    }
    // biases in C/D layout
    float bbias[4][4];
    #pragma unroll
    for (int mt = 0; mt < 4; ++mt)
        #pragma unroll
        for (int r = 0; r < 4; ++r) bbias[mt][r] = bb[mt * 16 + lq * 4 + r];
    float hbias[8][4];
    #pragma unroll
    for (int i = 0; i < 8; ++i) {
        const int u = i * 4 + lq;
        hbias[i][0] = bff1[u]; hbias[i][1] = bff2[u];
        hbias[i][2] = bta[u];  hbias[i][3] = btb[u];
    }

    // ------------- prologue: zero z, stage x_0 (wave-private) ------------
    #pragma unroll
    for (int i = 0; i < (NPIX * KPAD / 2) / 64; ++i)
        ((unsigned*)z)[lane + i * 64] = 0u;

    const int cstride = TSTEPS * HW;            // x channel stride
    const float* xp0 = x + (size_t)(b * CIN + lq * 4) * cstride + pinb + ln;
    const int xwr = swoff(ln, lq * 4);          // 4 consecutive k -> b64
    {
        short4v p;
        #pragma unroll
        for (int j = 0; j < 4; ++j) p[j] = (short)bf16_rne(xp0[j * cstride]);
        *(short4v*)&z[xwr] = p;
    }

    // hoisted offsets
    const int zrd0 = swoff(ln, lq * 8);
    const int zrd1 = swoff(ln, 32 + lq * 8);
    int awr[4];
    #pragma unroll
    for (int mt = 0; mt < 4; ++mt) awr[mt] = swoff(ln, mt * 16 + lq * 4);
    int hwr[8];
    #pragma unroll
    for (int i = 0; i < 8; ++i) hwr[i] = swoff(ln, CIN + i * 4 + lq);
    int oofs[8];
    #pragma unroll
    for (int i = 0; i < 8; ++i)
        oofs[i] = ((b * UNITS + i * 4 + lq) * TSTEPS) * HW + pinb + ln;
    int xo = HW;                                 // element offset of x_{t+1}

    // ------------- the scan: NO barriers, all deps in-wave ---------------
    #pragma unroll 1
    for (int t = 0; t < TSTEPS; ++t) {
        // prefetch x_{t+1} (consumed at the bottom of this step)
        float xv[4];
        #pragma unroll
        for (int j = 0; j < 4; ++j) xv[j] = xp0[j * cstride + xo];

        // backbone: z B-frags -> 4 m-tiles x 4 MFMA -> lecun_tanh -> a
        bf16x8 Z0 = __builtin_bit_cast(bf16x8, *(const short8*)&z[zrd0]);
        bf16x8 Z1 = __builtin_bit_cast(bf16x8, *(const short8*)&z[zrd1]);
        #pragma unroll
        for (int mt = 0; mt < 4; ++mt) {
            float4v acc = {bbias[mt][0], bbias[mt][1], bbias[mt][2], bbias[mt][3]};
            acc = mfma16(Wbh[mt][0], Z0, acc);
            acc = mfma16(Wbl[mt][0], Z0, acc);
            acc = mfma16(Wbh[mt][1], Z1, acc);
            acc = mfma16(Wbl[mt][1], Z1, acc);
            short4v ph;
            #pragma unroll
            for (int r = 0; r < 4; ++r)
                ph[r] = (short)bf16_rne(1.7159f * tanh_fast(0.666f * acc[r]));
            *(short4v*)&a[awr[mt]] = ph;        // in-wave lgkmcnt orders this
        }

        // heads: a B-frags -> 8 interleaved tiles x 4 MFMA -> gate -> out, h
        bf16x8 A0 = __builtin_bit_cast(bf16x8, *(const short8*)&a[zrd0]);
        bf16x8 A1 = __builtin_bit_cast(bf16x8, *(const short8*)&a[zrd1]);
        #pragma unroll
        for (int i = 0; i < 8; ++i) {
            float4v acc = {hbias[i][0], hbias[i][1], hbias[i][2], hbias[i][3]};
            acc = mfma16(Whh[i][0], A0, acc);
            acc = mfma16(Whl[i][0], A0, acc);
            acc = mfma16(Whh[i][1], A1, acc);
            acc = mfma16(Whl[i][1], A1, acc);
            float f1 = tanh_fast(acc[0]);
            float f2 = tanh_fast(acc[1]);
            float ti = sigmoid_fast(acc[2] + acc[3]);
            float hn = f1 + ti * (f2 - f1);
            out[oofs[i]] = hn;
            oofs[i] += HW;
            z[hwr[i]] = bf16_rne(hn);           // h feedback (k = 16+u)
        }

        // stage x_{t+1} into z (k = 0..15)
        {
            short4v p;
            #pragma unroll
            for (int j = 0; j < 4; ++j) p[j] = (short)bf16_rne(xv[j]);
            *(short4v*)&z[xwr] = p;
        }
        xo += (t < TSTEPS - 2) ? HW : 0;        // clamp prefetch at x_31
    }
}

extern "C" void kernel_launch(void* const* d_in, const int* in_sizes, int n_in,
                              void* d_out, int out_size, void* d_ws, size_t ws_size,
                              hipStream_t stream) {
    dim3 grid(4 * HW / NPIX);   // 1024 single-wave blocks -> 1 wave/SIMD
    cfc_wave_kernel<<<grid, 64, 0, stream>>>(
        (const float*)d_in[0], (const float*)d_in[1], (const float*)d_in[2],
        (const float*)d_in[3], (const float*)d_in[4], (const float*)d_in[5],
        (const float*)d_in[6], (const float*)d_in[7], (const float*)d_in[8],
        (const float*)d_in[9], (const float*)d_in[10],
        (float*)d_out);
}